// Round 19
// baseline (165.749 us; speedup 1.0000x reference)
//
#include <hip/hip_runtime.h>
#include <hip/hip_bf16.h>
#include <math.h>

typedef unsigned short u16;
typedef unsigned char u8;
typedef unsigned int u32;
typedef __attribute__((ext_vector_type(8))) short bf16x8;   // 8 bf16 in 4 VGPRs
typedef __attribute__((ext_vector_type(4))) float f32x4;

// ---------- bf16 helpers ----------
__device__ __forceinline__ float b2f(u16 u) {
  union { unsigned int i; float f; } x; x.i = ((unsigned int)u) << 16; return x.f;
}
__device__ __forceinline__ u16 f2b(float f) {
  union { float f; unsigned int i; } x; x.f = f;
  unsigned int r = x.i + 0x7FFFu + ((x.i >> 16) & 1u);
  return (u16)(r >> 16);
}
__device__ __forceinline__ float4 cvt4(ushort4 u) {
  return make_float4(b2f(u.x), b2f(u.y), b2f(u.z), b2f(u.w));
}
__device__ __forceinline__ float4 i8x4_to_f4(u32 w) {
  return make_float4((float)((int)(w << 24) >> 24), (float)((int)(w << 16) >> 24),
                     (float)((int)(w << 8) >> 24), (float)((int)w >> 24));
}

#if __has_builtin(__builtin_amdgcn_sdot4)
__device__ __forceinline__ int dot4i8(u32 a, u32 b) {
  return __builtin_amdgcn_sdot4((int)a, (int)b, 0, false);
}
#else
__device__ __forceinline__ int dot4i8(u32 a, u32 b) {
  int s = ((int)(a << 24) >> 24) * ((int)(b << 24) >> 24);
  s += ((int)(a << 16) >> 24) * ((int)(b << 16) >> 24);
  s += ((int)(a << 8) >> 24) * ((int)(b << 8) >> 24);
  s += ((int)a >> 24) * ((int)b >> 24);
  return s;
}
#endif

// int64-vs-int32 edge layout probe: 8 uniform scalar loads, all-zero odd words => int64.
__device__ __forceinline__ bool ei_is_i64(const int* __restrict__ ei) {
  return (ei[1] | ei[3] | ei[5] | ei[7] | ei[9] | ei[11] | ei[13] | ei[15]) == 0;
}

// ---------- prep: weight transpose (fragment-ordered) + edge count/rank (fused) --------
__global__ __launch_bounds__(256) void prep_kernel(
    const float* __restrict__ Wq, const float* __restrict__ Wk,
    const float* __restrict__ Wv, const float* __restrict__ Wsk,
    const float* __restrict__ Wd,
    const float* __restrict__ bq, const float* __restrict__ bk,
    const float* __restrict__ bv, const float* __restrict__ bsk,
    const float* __restrict__ bd,
    short* __restrict__ Wt, float* __restrict__ bias,
    const int* __restrict__ ei, int* __restrict__ cnt,
    u8* __restrict__ rank, int E) {
  int g = blockIdx.x * 256 + threadIdx.x;
  if (g < 5 * 16384) {
    int mat = g >> 14, rem = g & 16383;
    int frag = rem >> 9;            // nt*4+s
    int l = (rem >> 3) & 63;
    int j = rem & 7;
    int nt = frag >> 2, s = frag & 3;
    int nrow = nt * 16 + (l & 15);
    int kcol = s * 32 + (l >> 4) * 8 + j;
    const float* W = (mat == 0) ? Wq : (mat == 1) ? Wk : (mat == 2) ? Wv
                     : (mat == 3) ? Wsk : Wd;
    float scl = (mat == 0) ? 0.125f : 1.f;
    Wt[g] = (short)f2b(W[kcol * 128 + nrow] * scl);
  }
  if (g < 5 * 128) {
    int mat = g >> 7, nn = g & 127;
    const float* B = (mat == 0) ? bq : (mat == 1) ? bk : (mat == 2) ? bv
                     : (mat == 3) ? bsk : bd;
    bias[g] = B[nn] * ((mat == 0) ? 0.125f : 1.f);
  }
  bool f = ei_is_i64(ei);
  if (g < E) {
    int idx = f ? (g << 1) : g;
    int dbase = f ? (E << 1) : E;
    int d = ei[dbase + idx];
    rank[g] = (u8)atomicAdd(&cnt[d], 1);
  }
}

// multiblock scan: A = per-block exclusive scan + block total
__global__ __launch_bounds__(1024) void scanA_kernel(const int* __restrict__ cnt,
                                                     int* __restrict__ offs,
                                                     int* __restrict__ parts, int n) {
  __shared__ int wsum[16];
  int i = blockIdx.x * 1024 + threadIdx.x;
  int lane = threadIdx.x & 63, wid = threadIdx.x >> 6;
  int v = (i < n) ? cnt[i] : 0;
  int s = v;
#pragma unroll
  for (int off = 1; off < 64; off <<= 1) {
    int t = __shfl_up(s, off, 64);
    if (lane >= off) s += t;
  }
  if (lane == 63) wsum[wid] = s;
  __syncthreads();
  if (threadIdx.x == 0) {
    int acc = 0;
#pragma unroll
    for (int w = 0; w < 16; ++w) { int t = wsum[w]; wsum[w] = acc; acc += t; }
    parts[blockIdx.x] = acc;
  }
  __syncthreads();
  if (i < n) offs[i] = wsum[wid] + (s - v);
}

// C = (inline B) wave-scan of block totals + add base, finalize offs
__global__ __launch_bounds__(1024) void scanC_kernel(int* __restrict__ offs,
                                                     const int* __restrict__ parts,
                                                     int n, int nb) {
  __shared__ int sh[2];
  if (threadIdx.x < 64) {
    int lane = threadIdx.x;
    int v = (lane < nb) ? parts[lane] : 0;
    int s = v;
#pragma unroll
    for (int off = 1; off < 64; off <<= 1) {
      int t = __shfl_up(s, off, 64);
      if (lane >= off) s += t;
    }
    int base = __shfl(s - v, blockIdx.x, 64);
    int tot  = __shfl(s, nb - 1, 64);
    if (lane == 0) { sh[0] = base; sh[1] = tot; }
  }
  __syncthreads();
  int i = blockIdx.x * 1024 + threadIdx.x;
  if (i < n) offs[i] += sh[0];
  if (i == 0) offs[n] = sh[1];
}

// ---------- fused projections via MFMA: 64 rows/block as two pipelined half-tiles ------
// Both halves' x loads are issued before the first barrier (2x in-flight bytes),
// then each 32-row half runs MFMA + epilogue + copy-out (epilogue LDS reused).
__global__ __launch_bounds__(512) void proj_kernel(const float* __restrict__ x,
    const short* __restrict__ Wt, const float* __restrict__ bias,
    u32* __restrict__ q8, float* __restrict__ qscb,
    u32* __restrict__ kvq, float* __restrict__ scb,
    u32* __restrict__ skip32, int n,
    const int* __restrict__ ei, const int* __restrict__ offs,
    const u8* __restrict__ rank, int* __restrict__ csr, int E) {
  __shared__ short xt[2][32 * 128];
  __shared__ u32 qsL[32 * 33];
  __shared__ u32 kvL[32 * 65];
  __shared__ u32 skL[32 * 65];
  __shared__ float qscL[32 * 2];
  __shared__ float scL[32 * 4];
  int m0 = blockIdx.x * 64;
  int tid = threadIdx.x;

  // stage BOTH half-tiles (loads for both issued before the barrier)
  {
    int row = tid >> 4, c = tid & 15;     // 512 threads = 32 rows x 16 chunks
#pragma unroll
    for (int ph = 0; ph < 2; ++ph) {
      int grow = m0 + ph * 32 + row;
      bf16x8 val;
      if (grow < n) {
        const float* sp = x + (size_t)grow * 128 + c * 8;
        float4 f0 = *(const float4*)sp;
        float4 f1 = *(const float4*)(sp + 4);
        val[0] = (short)f2b(f0.x); val[1] = (short)f2b(f0.y);
        val[2] = (short)f2b(f0.z); val[3] = (short)f2b(f0.w);
        val[4] = (short)f2b(f1.x); val[5] = (short)f2b(f1.y);
        val[6] = (short)f2b(f1.z); val[7] = (short)f2b(f1.w);
      } else {
#pragma unroll
        for (int j = 0; j < 8; ++j) val[j] = 0;
      }
      *(bf16x8*)&xt[ph][row * 128 + ((c ^ (row & 15)) << 3)] = val;
    }
  }
  __syncthreads();

  int wid = tid >> 6, l = tid & 63;
  int mat = wid & 3, mhalf = wid >> 2;
  int lm = l & 15, lk = l >> 4;
  const short* Wl = Wt + (size_t)mat * 16384 + l * 8;   // fragment-ordered layout
  int ml = mhalf * 16 + lm;
  int lrow = mhalf * 16 + lm;   // local node row 0..31 within half

  for (int ph = 0; ph < 2; ++ph) {
    int mb = m0 + ph * 32;
    f32x4 acc[8];
#pragma unroll
    for (int nt = 0; nt < 8; ++nt) acc[nt] = (f32x4){0.f, 0.f, 0.f, 0.f};

#pragma unroll
    for (int s = 0; s < 4; ++s) {
      int c = s * 4 + lk;
      bf16x8 bfrag = *(const bf16x8*)&xt[ph][ml * 128 + ((c ^ (ml & 15)) << 3)];
#pragma unroll
      for (int nt = 0; nt < 8; ++nt) {
        bf16x8 afrag = *(const bf16x8*)(Wl + nt * 2048 + s * 512);
        acc[nt] = __builtin_amdgcn_mfma_f32_16x16x32_bf16(afrag, bfrag, acc[nt], 0, 0, 0);
      }
    }

    const float* bs = bias + mat * 128;
#pragma unroll
    for (int nt = 0; nt < 8; ++nt) {
      float4 b4 = *(const float4*)(bs + nt * 16 + lk * 4);
      acc[nt][0] += b4.x; acc[nt][1] += b4.y;
      acc[nt][2] += b4.z; acc[nt][3] += b4.w;
    }
    if (mat < 3) {
#pragma unroll
      for (int h = 0; h < 2; ++h) {
        float am = 0.f;
#pragma unroll
        for (int nt4 = 0; nt4 < 4; ++nt4) {
          int nt = h * 4 + nt4;
#pragma unroll
          for (int j = 0; j < 4; ++j) am = fmaxf(am, fabsf(acc[nt][j]));
        }
        am = fmaxf(am, __shfl_xor(am, 16));   // reduce over lk (lane bits 4,5)
        am = fmaxf(am, __shfl_xor(am, 32));
        float inv = (am > 0.f) ? 127.f / am : 0.f;
#pragma unroll
        for (int nt4 = 0; nt4 < 4; ++nt4) {
          int nt = h * 4 + nt4;
          u32 pk = 0;
#pragma unroll
          for (int j = 0; j < 4; ++j) {
            float qv = fminf(fmaxf(rintf(acc[nt][j] * inv), -127.f), 127.f);
            pk |= ((u32)((int)qv & 0xff)) << (8 * j);
          }
          int slot = nt4 * 4 + lk;
          if (mat == 0) qsL[lrow * 33 + h * 16 + slot] = pk;
          else kvL[lrow * 65 + h * 32 + slot * 2 + (mat - 1)] = pk;
        }
        if (lk == 0) {
          float sc = am * (1.f / 127.f);
          if (mat == 0) qscL[lrow * 2 + h] = sc;
          else scL[lrow * 4 + h * 2 + (mat - 1)] = sc;
        }
      }
    } else {
#pragma unroll
      for (int nt = 0; nt < 8; ++nt) {
        u16 o0 = f2b(acc[nt][0]), o1 = f2b(acc[nt][1]);
        u16 o2 = f2b(acc[nt][2]), o3 = f2b(acc[nt][3]);
        int u = nt * 8 + lk * 2;   // u32 index within 64-u32 row
        skL[lrow * 65 + u]     = (u32)o0 | ((u32)o1 << 16);
        skL[lrow * 65 + u + 1] = (u32)o2 | ((u32)o3 << 16);
      }
    }
    __syncthreads();

    // coalesced copy-out for this half
    int nvalid = n - mb;
    if (nvalid > 32) nvalid = 32;
    if (nvalid > 0) {
      for (int idx = tid; idx < nvalid * 32; idx += 512) {
        int node = idx >> 5, slot = idx & 31;
        q8[(size_t)(mb + node) * 32 + slot] = qsL[node * 33 + slot];
      }
      for (int idx = tid; idx < nvalid * 64; idx += 512) {
        int node = idx >> 6, slot = idx & 63;
        kvq[(size_t)(mb + node) * 64 + slot] = kvL[node * 65 + slot];
      }
      for (int idx = tid; idx < nvalid * 64; idx += 512) {
        int node = idx >> 6, slot = idx & 63;
        skip32[(size_t)(mb + node) * 64 + slot] = skL[node * 65 + slot];
      }
      for (int idx = tid; idx < nvalid * 4; idx += 512) {
        int node = idx >> 2, s = idx & 3;
        scb[(size_t)(mb + node) * 4 + s] = scL[node * 4 + s];
      }
      for (int idx = tid; idx < nvalid * 2; idx += 512) {
        int node = idx >> 1, h = idx & 1;
        qscb[(size_t)(mb + node) * 2 + h] = qscL[node * 2 + h];
      }
    }
    __syncthreads();   // protect epilogue LDS reuse for next half
  }

  // tail scatter (attn is a later dispatch)
  {
    bool f = ei_is_i64(ei);
    int stride = gridDim.x * 512;
    for (int e = blockIdx.x * 512 + tid; e < E; e += stride) {
      int idx = f ? (e << 1) : e;
      int dbase = f ? (E << 1) : E;
      int s = ei[idx];
      int d = ei[dbase + idx];
      int pos = offs[d] + (int)rank[e];
      __builtin_nontemporal_store(s, &csr[pos]);
    }
  }
}

// ---------- decoder via MFMA, LDS-free: bfrag loaded directly global->reg ----------
__global__ __launch_bounds__(256) void dec_kernel(const float* __restrict__ zin,
    const short* __restrict__ Wt, const float* __restrict__ bias,
    float* __restrict__ out, int n) {
  int m0 = blockIdx.x * 128;
  int tid = threadIdx.x;
  int wid = tid >> 6, l = tid & 63;
  int lm = l & 15, lk = l >> 4;
  int mbase = wid * 32;
  const short* Wl = Wt + l * 8;   // fragment-ordered layout
  f32x4 acc[2][8];
#pragma unroll
  for (int mt = 0; mt < 2; ++mt)
#pragma unroll
    for (int nt = 0; nt < 8; ++nt) acc[mt][nt] = (f32x4){0.f, 0.f, 0.f, 0.f};

#pragma unroll
  for (int s = 0; s < 4; ++s) {
    bf16x8 bfrag[2];
#pragma unroll
    for (int mt = 0; mt < 2; ++mt) {
      int m = m0 + mbase + mt * 16 + lm;
      bf16x8 val;
      if (m < n) {
        const float* sp = zin + (size_t)m * 128 + s * 32 + lk * 8;
        float4 f0 = *(const float4*)sp;
        float4 f1 = *(const float4*)(sp + 4);
        val[0] = (short)f2b(f0.x); val[1] = (short)f2b(f0.y);
        val[2] = (short)f2b(f0.z); val[3] = (short)f2b(f0.w);
        val[4] = (short)f2b(f1.x); val[5] = (short)f2b(f1.y);
        val[6] = (short)f2b(f1.z); val[7] = (short)f2b(f1.w);
      } else {
#pragma unroll
        for (int j = 0; j < 8; ++j) val[j] = 0;
      }
      bfrag[mt] = val;
    }
#pragma unroll
    for (int nt = 0; nt < 8; ++nt) {
      bf16x8 afrag = *(const bf16x8*)(Wl + nt * 2048 + s * 512);
      acc[0][nt] = __builtin_amdgcn_mfma_f32_16x16x32_bf16(afrag, bfrag[0], acc[0][nt], 0, 0, 0);
      acc[1][nt] = __builtin_amdgcn_mfma_f32_16x16x32_bf16(afrag, bfrag[1], acc[1][nt], 0, 0, 0);
    }
  }

#pragma unroll
  for (int mt = 0; mt < 2; ++mt) {
    int m = m0 + mbase + mt * 16 + lm;
    if (m >= n) continue;
#pragma unroll
    for (int nt = 0; nt < 8; ++nt) {
      int n4 = nt * 16 + lk * 4;
      float4 b4 = *(const float4*)(bias + n4);
      f32x4 a = acc[mt][nt];
      *(float4*)(out + (size_t)m * 128 + n4) =
          make_float4(a[0] + b4.x, a[1] + b4.y, a[2] + b4.z, a[3] + b4.w);
    }
  }
}

// ---------- attention: ONE dst per wave; 64 lanes = 2 edges x 2 heads x 16 lanes -------
// (R13 structure — measured 47 us floor.)
#define PAIR_BODY(EA, EB, SACC, AACC, HM)                                    \
  {                                                                          \
    int e_ = half ? (EB) : (EA);                                             \
    u32 kvoff_ = (u32)e_ * 256u + (u32)(l32 * 8);                            \
    uint2 kv_ = *(const uint2*)(kvbytes + kvoff_);                           \
    float2 sc_ = *(const float2*)(scbytes + (u32)e_ * 16u + (u32)(h * 8));   \
    int pi_ = dot4i8(qw, kv_.x);                                             \
    pi_ += __shfl_xor(pi_, 1);                                               \
    pi_ += __shfl_xor(pi_, 2);                                               \
    pi_ += __shfl_xor(pi_, 4);                                               \
    pi_ += __shfl_xor(pi_, 8);                                               \
    float w_ = __expf((float)pi_ * (qs * sc_.x)) * (HM);                     \
    float4 vv_ = i8x4_to_f4(kv_.y);                                          \
    float wv_ = w_ * sc_.y;                                                  \
    SACC += w_;                                                              \
    AACC.x += wv_ * vv_.x; AACC.y += wv_ * vv_.y;                            \
    AACC.z += wv_ * vv_.z; AACC.w += wv_ * vv_.w;                            \
  }

__global__ __launch_bounds__(256) void attn_kernel(const u32* __restrict__ q8,
                                                   const float* __restrict__ qscb,
                                                   const u32* __restrict__ kvq,
                                                   const float* __restrict__ scb,
                                                   const u16* __restrict__ skipb,
                                                   const int* __restrict__ offs,
                                                   const int* __restrict__ csr,
                                                   float* __restrict__ z, int nn) {
  int wv = __builtin_amdgcn_readfirstlane((int)(threadIdx.x >> 6));
  int dst = blockIdx.x * 4 + wv;
  if (dst >= nn) return;
  int lane = threadIdx.x & 63;
  int half = lane >> 5;            // 0: even edge of pair, 1: odd edge
  int l32 = lane & 31;
  int h = l32 >> 4;                // head
  u32 qw = q8[(size_t)dst * 32 + l32];
  float qs = qscb[(size_t)dst * 2 + h];
  int i0 = __builtin_amdgcn_readfirstlane(offs[dst]);
  int i1 = __builtin_amdgcn_readfirstlane(offs[dst + 1]);
  const u8* kvbytes = (const u8*)kvq;
  const u8* scbytes = (const u8*)scb;
  float hm1 = (half == 0) ? 1.f : 0.f;   // mask for single-edge tail

  float s0 = 0.f, s1 = 0.f, s2 = 0.f, s3 = 0.f;
  float4 A0 = {0, 0, 0, 0}, A1 = {0, 0, 0, 0}, A2 = {0, 0, 0, 0}, A3 = {0, 0, 0, 0};

  int i = i0;
  for (; i + 7 < i1; i += 8) {
    int e0 = csr[i], e1 = csr[i + 1], e2 = csr[i + 2], e3 = csr[i + 3];
    int e4 = csr[i + 4], e5 = csr[i + 5], e6 = csr[i + 6], e7 = csr[i + 7];
    PAIR_BODY(e0, e1, s0, A0, 1.f)
    PAIR_BODY(e2, e3, s1, A1, 1.f)
    PAIR_BODY(e4, e5, s2, A2, 1.f)
    PAIR_BODY(e6, e7, s3, A3, 1.f)
  }
  for (; i + 1 < i1; i += 2) {
    int e0 = csr[i], e1 = csr[i + 1];
    PAIR_BODY(e0, e1, s0, A0, 1.f)
  }
  if (i < i1) {
    int e0 = csr[i];
    PAIR_BODY(e0, e0, s0, A0, hm1)
  }

  float sum = (s0 + s1) + (s2 + s3);
  float b0 = (A0.x + A1.x) + (A2.x + A3.x);
  float b1 = (A0.y + A1.y) + (A2.y + A3.y);
  float b2 = (A0.z + A1.z) + (A2.z + A3.z);
  float b3 = (A0.w + A1.w) + (A2.w + A3.w);
  // merge the two edge-halves of the wave
  sum += __shfl_xor(sum, 32);
  b0 += __shfl_xor(b0, 32);
  b1 += __shfl_xor(b1, 32);
  b2 += __shfl_xor(b2, 32);
  b3 += __shfl_xor(b3, 32);
  if (half == 0) {
    float inv = 1.f / (sum + 1e-16f);
    int qoff = dst * 128 + h * 64 + (l32 & 15) * 4;
    float4 sk = cvt4(*(const ushort4*)(skipb + qoff));
    *(float4*)(z + qoff) = make_float4(b0 * inv + sk.x, b1 * inv + sk.y,
                                       b2 * inv + sk.z, b3 * inv + sk.w);
  }
}

// ---------- launch ----------
extern "C" void kernel_launch(void* const* d_in, const int* in_sizes, int n_in,
                              void* d_out, int out_size, void* d_ws, size_t ws_size,
                              hipStream_t stream) {
  const float* x  = (const float*)d_in[0];
  const int*   ei = (const int*)d_in[1];
  const float* Wq = (const float*)d_in[2];
  const float* bq = (const float*)d_in[3];
  const float* Wk = (const float*)d_in[4];
  const float* bk = (const float*)d_in[5];
  const float* Wv = (const float*)d_in[6];
  const float* bv = (const float*)d_in[7];
  const float* Wsk = (const float*)d_in[8];
  const float* bsk = (const float*)d_in[9];
  const float* Wd = (const float*)d_in[10];
  const float* bd = (const float*)d_in[11];

  int N = in_sizes[0] / 128;
  int E = in_sizes[1] / 2;

  char* w = (char*)d_ws;
  auto alloc = [&](size_t bytes) {
    char* p = w;
    w += (bytes + 255) & ~(size_t)255;
    return p;
  };
  u32* q8    = (u32*)alloc((size_t)N * 32 * 4);
  float* qscb = (float*)alloc((size_t)N * 2 * 4);
  u32* kvq   = (u32*)alloc((size_t)N * 64 * 4);
  float* scb = (float*)alloc((size_t)N * 4 * 4);
  u16* skipb = (u16*)alloc((size_t)N * 128 * 2);
  int* cnt  = (int*)alloc((size_t)(N + 1) * 4);
  int* offs = (int*)alloc((size_t)(N + 1) * 4);
  u8*  rank = (u8*)alloc((size_t)E);
  int* csr  = (int*)alloc((size_t)E * 4);
  int* parts = (int*)alloc(66 * 4);
  short* Wt = (short*)alloc(5 * 16384 * 2);
  float* bias = (float*)alloc(5 * 128 * 4);

  float* xhat = (float*)d_out;               // output 0: [N,128] fp32
  float* z = xhat + (size_t)N * 128;         // output 1: [N,128] fp32

  int nb = (N + 1023) / 1024;                // 49 for N=50000 (must be <= 64)
  int gp = (E + 255) / 256;                  // prep grid covers E (>= 81920 too)
  if (gp < 320) gp = 320;

  // cnt zeroing (graph-capturable memset node)
  hipMemsetAsync(cnt, 0, (size_t)N * 4, stream);
  // fused weight prep + edge count/rank
  prep_kernel<<<gp, 256, 0, stream>>>(Wq, Wk, Wv, Wsk, Wd, bq, bk, bv, bsk, bd,
                                      Wt, bias, ei, cnt, rank, E);
  scanA_kernel<<<nb, 1024, 0, stream>>>(cnt, offs, parts, N);
  scanC_kernel<<<nb, 1024, 0, stream>>>(offs, parts, N, nb);

  // fused projections (64 rows/block, pipelined halves) + tail CSR scatter
  proj_kernel<<<(N + 63) / 64, 512, 0, stream>>>(x, Wt, bias, q8, qscb, kvq, scb,
                                                 (u32*)skipb, N, ei, offs, rank,
                                                 csr, E);

  // attention: one dst per wave (R13 structure)
  attn_kernel<<<(N + 3) / 4, 256, 0, stream>>>(q8, qscb, kvq, scb, skipb, offs, csr,
                                               z, N);

  // decoder (LDS-free): xhat = z @ Wdec + bdec
  dec_kernel<<<(N + 127) / 128, 256, 0, stream>>>(z, Wt + 4 * 16384, bias + 4 * 128,
                                                  xhat, N);
}

// Round 20
// 155.414 us; speedup vs baseline: 1.0665x; 1.0665x over previous
//
#include <hip/hip_runtime.h>
#include <hip/hip_bf16.h>
#include <math.h>

typedef unsigned short u16;
typedef unsigned char u8;
typedef unsigned int u32;
typedef __attribute__((ext_vector_type(8))) short bf16x8;   // 8 bf16 in 4 VGPRs
typedef __attribute__((ext_vector_type(4))) float f32x4;

// ---------- bf16 helpers ----------
__device__ __forceinline__ float b2f(u16 u) {
  union { unsigned int i; float f; } x; x.i = ((unsigned int)u) << 16; return x.f;
}
__device__ __forceinline__ u16 f2b(float f) {
  union { float f; unsigned int i; } x; x.f = f;
  unsigned int r = x.i + 0x7FFFu + ((x.i >> 16) & 1u);
  return (u16)(r >> 16);
}
__device__ __forceinline__ float4 cvt4(ushort4 u) {
  return make_float4(b2f(u.x), b2f(u.y), b2f(u.z), b2f(u.w));
}
__device__ __forceinline__ float4 i8x4_to_f4(u32 w) {
  return make_float4((float)((int)(w << 24) >> 24), (float)((int)(w << 16) >> 24),
                     (float)((int)(w << 8) >> 24), (float)((int)w >> 24));
}

#if __has_builtin(__builtin_amdgcn_sdot4)
__device__ __forceinline__ int dot4i8(u32 a, u32 b) {
  return __builtin_amdgcn_sdot4((int)a, (int)b, 0, false);
}
#else
__device__ __forceinline__ int dot4i8(u32 a, u32 b) {
  int s = ((int)(a << 24) >> 24) * ((int)(b << 24) >> 24);
  s += ((int)(a << 16) >> 24) * ((int)(b << 16) >> 24);
  s += ((int)(a << 8) >> 24) * ((int)(b << 8) >> 24);
  s += ((int)a >> 24) * ((int)b >> 24);
  return s;
}
#endif

// int64-vs-int32 edge layout probe: 8 uniform scalar loads, all-zero odd words => int64.
__device__ __forceinline__ bool ei_is_i64(const int* __restrict__ ei) {
  return (ei[1] | ei[3] | ei[5] | ei[7] | ei[9] | ei[11] | ei[13] | ei[15]) == 0;
}

// ---------- prep: weight transpose (fragment-ordered) + edge count/rank (fused) --------
__global__ __launch_bounds__(256) void prep_kernel(
    const float* __restrict__ Wq, const float* __restrict__ Wk,
    const float* __restrict__ Wv, const float* __restrict__ Wsk,
    const float* __restrict__ Wd,
    const float* __restrict__ bq, const float* __restrict__ bk,
    const float* __restrict__ bv, const float* __restrict__ bsk,
    const float* __restrict__ bd,
    short* __restrict__ Wt, float* __restrict__ bias,
    const int* __restrict__ ei, int* __restrict__ cnt,
    u8* __restrict__ rank, int E) {
  int g = blockIdx.x * 256 + threadIdx.x;
  if (g < 5 * 16384) {
    int mat = g >> 14, rem = g & 16383;
    int frag = rem >> 9;            // nt*4+s
    int l = (rem >> 3) & 63;
    int j = rem & 7;
    int nt = frag >> 2, s = frag & 3;
    int nrow = nt * 16 + (l & 15);
    int kcol = s * 32 + (l >> 4) * 8 + j;
    const float* W = (mat == 0) ? Wq : (mat == 1) ? Wk : (mat == 2) ? Wv
                     : (mat == 3) ? Wsk : Wd;
    float scl = (mat == 0) ? 0.125f : 1.f;
    Wt[g] = (short)f2b(W[kcol * 128 + nrow] * scl);
  }
  if (g < 5 * 128) {
    int mat = g >> 7, nn = g & 127;
    const float* B = (mat == 0) ? bq : (mat == 1) ? bk : (mat == 2) ? bv
                     : (mat == 3) ? bsk : bd;
    bias[g] = B[nn] * ((mat == 0) ? 0.125f : 1.f);
  }
  bool f = ei_is_i64(ei);
  if (g < E) {
    int idx = f ? (g << 1) : g;
    int dbase = f ? (E << 1) : E;
    int d = ei[dbase + idx];
    rank[g] = (u8)atomicAdd(&cnt[d], 1);
  }
}

// multiblock scan: A = per-block exclusive scan + block total
__global__ __launch_bounds__(1024) void scanA_kernel(const int* __restrict__ cnt,
                                                     int* __restrict__ offs,
                                                     int* __restrict__ parts, int n) {
  __shared__ int wsum[16];
  int i = blockIdx.x * 1024 + threadIdx.x;
  int lane = threadIdx.x & 63, wid = threadIdx.x >> 6;
  int v = (i < n) ? cnt[i] : 0;
  int s = v;
#pragma unroll
  for (int off = 1; off < 64; off <<= 1) {
    int t = __shfl_up(s, off, 64);
    if (lane >= off) s += t;
  }
  if (lane == 63) wsum[wid] = s;
  __syncthreads();
  if (threadIdx.x == 0) {
    int acc = 0;
#pragma unroll
    for (int w = 0; w < 16; ++w) { int t = wsum[w]; wsum[w] = acc; acc += t; }
    parts[blockIdx.x] = acc;
  }
  __syncthreads();
  if (i < n) offs[i] = wsum[wid] + (s - v);
}

// C = (inline B) wave-scan of block totals + add base, finalize offs
__global__ __launch_bounds__(1024) void scanC_kernel(int* __restrict__ offs,
                                                     const int* __restrict__ parts,
                                                     int n, int nb) {
  __shared__ int sh[2];
  if (threadIdx.x < 64) {
    int lane = threadIdx.x;
    int v = (lane < nb) ? parts[lane] : 0;
    int s = v;
#pragma unroll
    for (int off = 1; off < 64; off <<= 1) {
      int t = __shfl_up(s, off, 64);
      if (lane >= off) s += t;
    }
    int base = __shfl(s - v, blockIdx.x, 64);
    int tot  = __shfl(s, nb - 1, 64);
    if (lane == 0) { sh[0] = base; sh[1] = tot; }
  }
  __syncthreads();
  int i = blockIdx.x * 1024 + threadIdx.x;
  if (i < n) offs[i] += sh[0];
  if (i == 0) offs[n] = sh[1];
}

// ---------- fused projections via MFMA (8 waves) + LDS-bounced outputs + CSR scatter ---
// (R15 configuration — best measured: 156.08 us total, 48 VGPR, 35% occupancy.)
__global__ __launch_bounds__(512) void proj_kernel(const float* __restrict__ x,
    const short* __restrict__ Wt, const float* __restrict__ bias,
    u32* __restrict__ q8, float* __restrict__ qscb,
    u32* __restrict__ kvq, float* __restrict__ scb,
    u32* __restrict__ skip32, int n,
    const int* __restrict__ ei, const int* __restrict__ offs,
    const u8* __restrict__ rank, int* __restrict__ csr, int E) {
  __shared__ short xt[32 * 128];
  __shared__ u32 qsL[32 * 33];
  __shared__ u32 kvL[32 * 65];
  __shared__ u32 skL[32 * 65];
  __shared__ float qscL[32 * 2];
  __shared__ float scL[32 * 4];
  int m0 = blockIdx.x * 32;
  int tid = threadIdx.x;

  // fused scatter
  {
    bool f = ei_is_i64(ei);
    int stride = gridDim.x * 512;
    for (int e = blockIdx.x * 512 + tid; e < E; e += stride) {
      int idx = f ? (e << 1) : e;
      int dbase = f ? (E << 1) : E;
      int s = ei[idx];
      int d = ei[dbase + idx];
      int pos = offs[d] + (int)rank[e];
      __builtin_nontemporal_store(s, &csr[pos]);
    }
  }

  {
    int row = tid >> 4, c = tid & 15;     // 512 threads = 32 rows x 16 chunks
    int grow = m0 + row;
    bf16x8 val;
    if (grow < n) {
      const float* sp = x + (size_t)grow * 128 + c * 8;
      float4 f0 = *(const float4*)sp;
      float4 f1 = *(const float4*)(sp + 4);
      val[0] = (short)f2b(f0.x); val[1] = (short)f2b(f0.y);
      val[2] = (short)f2b(f0.z); val[3] = (short)f2b(f0.w);
      val[4] = (short)f2b(f1.x); val[5] = (short)f2b(f1.y);
      val[6] = (short)f2b(f1.z); val[7] = (short)f2b(f1.w);
    } else {
#pragma unroll
      for (int j = 0; j < 8; ++j) val[j] = 0;
    }
    *(bf16x8*)&xt[row * 128 + ((c ^ (row & 15)) << 3)] = val;
  }
  __syncthreads();

  int wid = tid >> 6, l = tid & 63;
  int mat = wid & 3, mhalf = wid >> 2;
  int lm = l & 15, lk = l >> 4;
  const short* Wl = Wt + (size_t)mat * 16384 + l * 8;   // fragment-ordered layout
  int ml = mhalf * 16 + lm;
  f32x4 acc[8];
#pragma unroll
  for (int nt = 0; nt < 8; ++nt) acc[nt] = (f32x4){0.f, 0.f, 0.f, 0.f};

#pragma unroll
  for (int s = 0; s < 4; ++s) {
    int c = s * 4 + lk;
    bf16x8 bfrag = *(const bf16x8*)&xt[ml * 128 + ((c ^ (ml & 15)) << 3)];
#pragma unroll
    for (int nt = 0; nt < 8; ++nt) {
      bf16x8 afrag = *(const bf16x8*)(Wl + nt * 2048 + s * 512);
      acc[nt] = __builtin_amdgcn_mfma_f32_16x16x32_bf16(afrag, bfrag, acc[nt], 0, 0, 0);
    }
  }

  const float* bs = bias + mat * 128;
#pragma unroll
  for (int nt = 0; nt < 8; ++nt) {
    float4 b4 = *(const float4*)(bs + nt * 16 + lk * 4);
    acc[nt][0] += b4.x; acc[nt][1] += b4.y;
    acc[nt][2] += b4.z; acc[nt][3] += b4.w;
  }
  int lrow = mhalf * 16 + lm;   // local node row 0..31
  if (mat < 3) {
#pragma unroll
    for (int h = 0; h < 2; ++h) {
      float am = 0.f;
#pragma unroll
      for (int nt4 = 0; nt4 < 4; ++nt4) {
        int nt = h * 4 + nt4;
#pragma unroll
        for (int j = 0; j < 4; ++j) am = fmaxf(am, fabsf(acc[nt][j]));
      }
      am = fmaxf(am, __shfl_xor(am, 16));   // reduce over lk (lane bits 4,5)
      am = fmaxf(am, __shfl_xor(am, 32));
      float inv = (am > 0.f) ? 127.f / am : 0.f;
#pragma unroll
      for (int nt4 = 0; nt4 < 4; ++nt4) {
        int nt = h * 4 + nt4;
        u32 pk = 0;
#pragma unroll
        for (int j = 0; j < 4; ++j) {
          float qv = fminf(fmaxf(rintf(acc[nt][j] * inv), -127.f), 127.f);
          pk |= ((u32)((int)qv & 0xff)) << (8 * j);
        }
        int slot = nt4 * 4 + lk;
        if (mat == 0) qsL[lrow * 33 + h * 16 + slot] = pk;
        else kvL[lrow * 65 + h * 32 + slot * 2 + (mat - 1)] = pk;
      }
      if (lk == 0) {
        float sc = am * (1.f / 127.f);
        if (mat == 0) qscL[lrow * 2 + h] = sc;
        else scL[lrow * 4 + h * 2 + (mat - 1)] = sc;
      }
    }
  } else {
#pragma unroll
    for (int nt = 0; nt < 8; ++nt) {
      u16 o0 = f2b(acc[nt][0]), o1 = f2b(acc[nt][1]);
      u16 o2 = f2b(acc[nt][2]), o3 = f2b(acc[nt][3]);
      int u = nt * 8 + lk * 2;   // u32 index within 64-u32 row
      skL[lrow * 65 + u]     = (u32)o0 | ((u32)o1 << 16);
      skL[lrow * 65 + u + 1] = (u32)o2 | ((u32)o3 << 16);
    }
  }
  __syncthreads();

  // coalesced copy-out
  int nvalid = n - m0; if (nvalid > 32) nvalid = 32;
  for (int idx = tid; idx < nvalid * 32; idx += 512) {
    int node = idx >> 5, slot = idx & 31;
    q8[(size_t)(m0 + node) * 32 + slot] = qsL[node * 33 + slot];
  }
  for (int idx = tid; idx < nvalid * 64; idx += 512) {
    int node = idx >> 6, slot = idx & 63;
    kvq[(size_t)(m0 + node) * 64 + slot] = kvL[node * 65 + slot];
  }
  for (int idx = tid; idx < nvalid * 64; idx += 512) {
    int node = idx >> 6, slot = idx & 63;
    skip32[(size_t)(m0 + node) * 64 + slot] = skL[node * 65 + slot];
  }
  for (int idx = tid; idx < nvalid * 4; idx += 512) {
    int node = idx >> 2, s = idx & 3;
    scb[(size_t)(m0 + node) * 4 + s] = scL[node * 4 + s];
  }
  for (int idx = tid; idx < nvalid * 2; idx += 512) {
    int node = idx >> 1, h = idx & 1;
    qscb[(size_t)(m0 + node) * 2 + h] = qscL[node * 2 + h];
  }
}

// ---------- decoder via MFMA: xhat = z @ Wdec + bdec (z fp32 staged->bf16) ----------
__global__ __launch_bounds__(256) void dec_kernel(const float* __restrict__ zin,
    const short* __restrict__ Wt, const float* __restrict__ bias,
    float* __restrict__ out, int n) {
  __shared__ short zt[128 * 128];
  int m0 = blockIdx.x * 128;
  int tid = threadIdx.x;
#pragma unroll
  for (int p = 0; p < 8; ++p) {
    int cid = tid + p * 256;
    int row = cid >> 4, c = cid & 15;
    int grow = m0 + row;
    bf16x8 val;
    if (grow < n) {
      const float* sp = zin + (size_t)grow * 128 + c * 8;
      float4 f0 = *(const float4*)sp;
      float4 f1 = *(const float4*)(sp + 4);
      val[0] = (short)f2b(f0.x); val[1] = (short)f2b(f0.y);
      val[2] = (short)f2b(f0.z); val[3] = (short)f2b(f0.w);
      val[4] = (short)f2b(f1.x); val[5] = (short)f2b(f1.y);
      val[6] = (short)f2b(f1.z); val[7] = (short)f2b(f1.w);
    } else {
#pragma unroll
      for (int j = 0; j < 8; ++j) val[j] = 0;
    }
    *(bf16x8*)&zt[row * 128 + ((c ^ (row & 15)) << 3)] = val;
  }
  __syncthreads();

  int wid = tid >> 6, l = tid & 63;
  int lm = l & 15, lk = l >> 4;
  int mbase = wid * 32;
  const short* Wl = Wt + l * 8;   // fragment-ordered layout
  f32x4 acc[2][8];
#pragma unroll
  for (int mt = 0; mt < 2; ++mt)
#pragma unroll
    for (int nt = 0; nt < 8; ++nt) acc[mt][nt] = (f32x4){0.f, 0.f, 0.f, 0.f};

#pragma unroll
  for (int s = 0; s < 4; ++s) {
    bf16x8 bfrag[2];
#pragma unroll
    for (int mt = 0; mt < 2; ++mt) {
      int ml = mbase + mt * 16 + lm;
      int c = s * 4 + lk;
      bfrag[mt] = *(const bf16x8*)&zt[ml * 128 + ((c ^ (ml & 15)) << 3)];
    }
#pragma unroll
    for (int nt = 0; nt < 8; ++nt) {
      bf16x8 afrag = *(const bf16x8*)(Wl + nt * 2048 + s * 512);
      acc[0][nt] = __builtin_amdgcn_mfma_f32_16x16x32_bf16(afrag, bfrag[0], acc[0][nt], 0, 0, 0);
      acc[1][nt] = __builtin_amdgcn_mfma_f32_16x16x32_bf16(afrag, bfrag[1], acc[1][nt], 0, 0, 0);
    }
  }

#pragma unroll
  for (int mt = 0; mt < 2; ++mt) {
    int m = m0 + mbase + mt * 16 + lm;
    if (m >= n) continue;
#pragma unroll
    for (int nt = 0; nt < 8; ++nt) {
      int n4 = nt * 16 + lk * 4;
      float4 b4 = *(const float4*)(bias + n4);
      f32x4 a = acc[mt][nt];
      *(float4*)(out + (size_t)m * 128 + n4) =
          make_float4(a[0] + b4.x, a[1] + b4.y, a[2] + b4.z, a[3] + b4.w);
    }
  }
}

// ---------- attention: ONE dst per wave; 64 lanes = 2 edges x 2 heads x 16 lanes -------
#define PAIR_BODY(EA, EB, SACC, AACC, HM)                                    \
  {                                                                          \
    int e_ = half ? (EB) : (EA);                                             \
    u32 kvoff_ = (u32)e_ * 256u + (u32)(l32 * 8);                            \
    uint2 kv_ = *(const uint2*)(kvbytes + kvoff_);                           \
    float2 sc_ = *(const float2*)(scbytes + (u32)e_ * 16u + (u32)(h * 8));   \
    int pi_ = dot4i8(qw, kv_.x);                                             \
    pi_ += __shfl_xor(pi_, 1);                                               \
    pi_ += __shfl_xor(pi_, 2);                                               \
    pi_ += __shfl_xor(pi_, 4);                                               \
    pi_ += __shfl_xor(pi_, 8);                                               \
    float w_ = __expf((float)pi_ * (qs * sc_.x)) * (HM);                     \
    float4 vv_ = i8x4_to_f4(kv_.y);                                          \
    float wv_ = w_ * sc_.y;                                                  \
    SACC += w_;                                                              \
    AACC.x += wv_ * vv_.x; AACC.y += wv_ * vv_.y;                            \
    AACC.z += wv_ * vv_.z; AACC.w += wv_ * vv_.w;                            \
  }

__global__ __launch_bounds__(256) void attn_kernel(const u32* __restrict__ q8,
                                                   const float* __restrict__ qscb,
                                                   const u32* __restrict__ kvq,
                                                   const float* __restrict__ scb,
                                                   const u16* __restrict__ skipb,
                                                   const int* __restrict__ offs,
                                                   const int* __restrict__ csr,
                                                   float* __restrict__ z, int nn) {
  int wv = __builtin_amdgcn_readfirstlane((int)(threadIdx.x >> 6));
  int dst = blockIdx.x * 4 + wv;
  if (dst >= nn) return;
  int lane = threadIdx.x & 63;
  int half = lane >> 5;            // 0: even edge of pair, 1: odd edge
  int l32 = lane & 31;
  int h = l32 >> 4;                // head
  u32 qw = q8[(size_t)dst * 32 + l32];
  float qs = qscb[(size_t)dst * 2 + h];
  int i0 = __builtin_amdgcn_readfirstlane(offs[dst]);
  int i1 = __builtin_amdgcn_readfirstlane(offs[dst + 1]);
  const u8* kvbytes = (const u8*)kvq;
  const u8* scbytes = (const u8*)scb;
  float hm1 = (half == 0) ? 1.f : 0.f;   // mask for single-edge tail

  float s0 = 0.f, s1 = 0.f, s2 = 0.f, s3 = 0.f;
  float4 A0 = {0, 0, 0, 0}, A1 = {0, 0, 0, 0}, A2 = {0, 0, 0, 0}, A3 = {0, 0, 0, 0};

  int i = i0;
  for (; i + 7 < i1; i += 8) {
    int e0 = csr[i], e1 = csr[i + 1], e2 = csr[i + 2], e3 = csr[i + 3];
    int e4 = csr[i + 4], e5 = csr[i + 5], e6 = csr[i + 6], e7 = csr[i + 7];
    PAIR_BODY(e0, e1, s0, A0, 1.f)
    PAIR_BODY(e2, e3, s1, A1, 1.f)
    PAIR_BODY(e4, e5, s2, A2, 1.f)
    PAIR_BODY(e6, e7, s3, A3, 1.f)
  }
  for (; i + 1 < i1; i += 2) {
    int e0 = csr[i], e1 = csr[i + 1];
    PAIR_BODY(e0, e1, s0, A0, 1.f)
  }
  if (i < i1) {
    int e0 = csr[i];
    PAIR_BODY(e0, e0, s0, A0, hm1)
  }

  float sum = (s0 + s1) + (s2 + s3);
  float b0 = (A0.x + A1.x) + (A2.x + A3.x);
  float b1 = (A0.y + A1.y) + (A2.y + A3.y);
  float b2 = (A0.z + A1.z) + (A2.z + A3.z);
  float b3 = (A0.w + A1.w) + (A2.w + A3.w);
  // merge the two edge-halves of the wave
  sum += __shfl_xor(sum, 32);
  b0 += __shfl_xor(b0, 32);
  b1 += __shfl_xor(b1, 32);
  b2 += __shfl_xor(b2, 32);
  b3 += __shfl_xor(b3, 32);
  if (half == 0) {
    float inv = 1.f / (sum + 1e-16f);
    int qoff = dst * 128 + h * 64 + (l32 & 15) * 4;
    float4 sk = cvt4(*(const ushort4*)(skipb + qoff));
    *(float4*)(z + qoff) = make_float4(b0 * inv + sk.x, b1 * inv + sk.y,
                                       b2 * inv + sk.z, b3 * inv + sk.w);
  }
}

// ---------- launch ----------
extern "C" void kernel_launch(void* const* d_in, const int* in_sizes, int n_in,
                              void* d_out, int out_size, void* d_ws, size_t ws_size,
                              hipStream_t stream) {
  const float* x  = (const float*)d_in[0];
  const int*   ei = (const int*)d_in[1];
  const float* Wq = (const float*)d_in[2];
  const float* bq = (const float*)d_in[3];
  const float* Wk = (const float*)d_in[4];
  const float* bk = (const float*)d_in[5];
  const float* Wv = (const float*)d_in[6];
  const float* bv = (const float*)d_in[7];
  const float* Wsk = (const float*)d_in[8];
  const float* bsk = (const float*)d_in[9];
  const float* Wd = (const float*)d_in[10];
  const float* bd = (const float*)d_in[11];

  int N = in_sizes[0] / 128;
  int E = in_sizes[1] / 2;

  char* w = (char*)d_ws;
  auto alloc = [&](size_t bytes) {
    char* p = w;
    w += (bytes + 255) & ~(size_t)255;
    return p;
  };
  u32* q8    = (u32*)alloc((size_t)N * 32 * 4);
  float* qscb = (float*)alloc((size_t)N * 2 * 4);
  u32* kvq   = (u32*)alloc((size_t)N * 64 * 4);
  float* scb = (float*)alloc((size_t)N * 4 * 4);
  u16* skipb = (u16*)alloc((size_t)N * 128 * 2);
  int* cnt  = (int*)alloc((size_t)(N + 1) * 4);
  int* offs = (int*)alloc((size_t)(N + 1) * 4);
  u8*  rank = (u8*)alloc((size_t)E);
  int* csr  = (int*)alloc((size_t)E * 4);
  int* parts = (int*)alloc(66 * 4);
  short* Wt = (short*)alloc(5 * 16384 * 2);
  float* bias = (float*)alloc(5 * 128 * 4);

  float* xhat = (float*)d_out;               // output 0: [N,128] fp32
  float* z = xhat + (size_t)N * 128;         // output 1: [N,128] fp32

  int nb = (N + 1023) / 1024;                // 49 for N=50000 (must be <= 64)
  int gp = (E + 255) / 256;                  // prep grid covers E (>= 81920 too)
  if (gp < 320) gp = 320;

  // cnt zeroing (graph-capturable memset node)
  hipMemsetAsync(cnt, 0, (size_t)N * 4, stream);
  // fused weight prep + edge count/rank
  prep_kernel<<<gp, 256, 0, stream>>>(Wq, Wk, Wv, Wsk, Wd, bq, bk, bv, bsk, bd,
                                      Wt, bias, ei, cnt, rank, E);
  scanA_kernel<<<nb, 1024, 0, stream>>>(cnt, offs, parts, N);
  scanC_kernel<<<nb, 1024, 0, stream>>>(offs, parts, N, nb);

  // fused projections + CSR scatter
  proj_kernel<<<(N + 31) / 32, 512, 0, stream>>>(x, Wt, bias, q8, qscb, kvq, scb,
                                                 (u32*)skipb, N, ei, offs, rank,
                                                 csr, E);

  // attention: one dst per wave (R13 structure)
  attn_kernel<<<(N + 3) / 4, 256, 0, stream>>>(q8, qscb, kvq, scb, skipb, offs, csr,
                                               z, N);

  // decoder: xhat = z @ Wdec + bdec
  dec_kernel<<<(N + 127) / 128, 256, 0, stream>>>(z, Wt + 4 * 16384, bias + 4 * 128,
                                                  xhat, N);
}